// Round 4
// baseline (5775.550 us; speedup 1.0000x reference)
//
#include <hip/hip_runtime.h>
#include <stdint.h>

// LSTM B=256,T=1024,I=64,H=256,O=1. fp32 in/out, bf16 MFMA internally.
//
// Round-4 design: NO per-step cross-block sync (rounds 1-3 showed the
// MALL-bypass exchange costs ~4-5k cyc/step regardless of round-trip count).
// 64 blocks: 32 CONSUMER blocks (one per 8-batch group) run the recurrence
// entirely on one CU: W_hh resident as 13/16 VGPR tiles + 3/16 LDS tiles per
// wave; per-step sync = 2 __syncthreads only. 32 PRODUCER blocks compute
// x_gates(t) = x(t)@W_ih^T + b_ih + b_hh a few steps ahead into a ring in
// d_ws (bypass stores), synced per-slot with flags — OFF the critical path
// (producer runs D slots ahead; consumer's flag check is speculative).
// Operand swap: mfma(A=W_frag, B=h_frag, acc) gives D[gate_row][batch]
// (C: col=lane&15=batch, row=quad*4+reg=gate row) so the epilogue writes
// xch[gate][batch][hidden] with b64 and the update phase reads b128.
// Flags/prog poison 0xAAAAAAAA is negative as int => no init kernel needed.

#define T_ 1024
#define I_ 64
#define H_ 256
#define NG 32
#define MBATCH 8

typedef float floatx4 __attribute__((ext_vector_type(4)));
typedef __bf16 bf16x8 __attribute__((ext_vector_type(8)));
typedef unsigned short ushortx8 __attribute__((ext_vector_type(8)));
typedef unsigned int uint32;
typedef unsigned long long u64;

__device__ __forceinline__ unsigned short f2bf(float f) {
  uint32 u = __builtin_bit_cast(uint32, f);
  u = (u + 0x7FFFu + ((u >> 16) & 1u)) >> 16;  // RNE
  return (unsigned short)u;
}
__device__ __forceinline__ float bf2f(uint32 u16) {
  uint32 u = u16 << 16;
  return __builtin_bit_cast(float, u);
}
__device__ __forceinline__ uint32 pack2bf(float a, float b) {
  return (uint32)f2bf(a) | ((uint32)f2bf(b) << 16);
}
__device__ __forceinline__ bf16x8 packbf8(floatx4 a, floatx4 b) {
  bf16x8 r;
  r[0] = (__bf16)a[0]; r[1] = (__bf16)a[1];
  r[2] = (__bf16)a[2]; r[3] = (__bf16)a[3];
  r[4] = (__bf16)b[0]; r[5] = (__bf16)b[1];
  r[6] = (__bf16)b[2]; r[7] = (__bf16)b[3];
  return r;
}
__device__ __forceinline__ float fast_sig(float v) {
  return 1.0f / (1.0f + __expf(-v));
}
__device__ __forceinline__ float fast_tanh(float v) {
  float e = __expf(2.0f * v);
  return 1.0f - 2.0f / (e + 1.0f);
}
__device__ __forceinline__ int aload(const int* p) {
  return __hip_atomic_load(p, __ATOMIC_RELAXED, __HIP_MEMORY_SCOPE_AGENT);
}
__device__ __forceinline__ u64 aload64(const u64* p) {
  return __hip_atomic_load(p, __ATOMIC_RELAXED, __HIP_MEMORY_SCOPE_AGENT);
}

__global__ __launch_bounds__(256, 1) void lstm_all(
    const float* __restrict__ x, const float* __restrict__ W_ih,
    const float* __restrict__ W_hh, const float* __restrict__ b_ih,
    const float* __restrict__ b_hh, const float* __restrict__ fc_w,
    const float* __restrict__ fc_b, float* __restrict__ out,
    int* __restrict__ prog, int* __restrict__ flags,
    unsigned short* __restrict__ ring, int D, int Dmask) {
  const int tid = threadIdx.x;
  const int bid = blockIdx.x;
  const int w = tid >> 6;      // wave = gate (i,f,g,o)
  const int lane = tid & 63;
  const int ln = lane & 15;
  const int q = lane >> 4;

  // consumer LDS (producers allocate but don't use it)
  __shared__ __align__(16) unsigned short lds_w[49152];   // 96 KB: [w][tl<3][kc<8][lane]x8
  __shared__ __align__(16) unsigned short xch[4 * 8 * 264];   // [gate][b][264]
  __shared__ __align__(16) unsigned short h_lds[16 * 280];    // [b(16)][280]

  if (bid < NG) {
    // ================= CONSUMER: the recurrence, one CU per group =========
    const int g = bid;
    // ---- W_hh fragments: 13 VGPR tiles + 3 LDS tiles per wave ----
    bf16x8 wf[13][8];
#pragma unroll
    for (int gt = 0; gt < 16; ++gt) {
      const int row = w * 256 + gt * 16 + ln;
#pragma unroll
      for (int kc = 0; kc < 8; ++kc) {
        const float* src = W_hh + (size_t)row * H_ + kc * 32 + q * 8;
        bf16x8 fr = packbf8(*(const floatx4*)src, *(const floatx4*)(src + 4));
        if (gt < 13) {
          wf[gt][kc] = fr;
        } else {
          *(ushortx8*)&lds_w[(((w * 3 + (gt - 13)) * 8 + kc) * 64 + lane) * 8] =
              __builtin_bit_cast(ushortx8, fr);
        }
      }
    }
    // zero h_lds (h0 = 0; rows 8..15 stay zero as harmless B-operand pad)
    {
      ushortx8 z = {0, 0, 0, 0, 0, 0, 0, 0};
      for (int i = tid; i < 560; i += 256) *(ushortx8*)&h_lds[i * 8] = z;
    }
    const int um = tid >> 5;            // update batch 0..7
    const int hb = (tid & 31) * 8;      // update hidden base (8 consecutive)
    float c[8];
#pragma unroll
    for (int j = 0; j < 8; ++j) c[j] = 0.0f;

    const unsigned short* ringg = ring + (size_t)g * D * 8192;
    u64 xgp[8];
    {  // preload x_gates(0)
      const int* f0 = flags + (g * D + 0) * 16;
      while (aload(f0) < 1) {
      }
      __atomic_signal_fence(__ATOMIC_SEQ_CST);
      const unsigned short* rs = ringg + um * 1024 + hb;
#pragma unroll
      for (int g4 = 0; g4 < 4; ++g4) {
        xgp[2 * g4] = aload64((const u64*)(rs + g4 * 256));
        xgp[2 * g4 + 1] = aload64((const u64*)(rs + g4 * 256) + 1);
      }
    }
    int flagv = aload(flags + (g * D + (1 & Dmask)) * 16);  // spec for t=1
    float partial = 0.0f;
    __syncthreads();

#pragma unroll 1
    for (int t = 0; t < T_; ++t) {
      // ---- MFMA: D[gate_row][batch], two tile-groups of 8 ----
      floatx4 acc[8];
#pragma unroll
      for (int lt = 0; lt < 8; ++lt) acc[lt] = (floatx4){0.f, 0.f, 0.f, 0.f};
#pragma unroll
      for (int kc = 0; kc < 8; ++kc) {
        bf16x8 hf = __builtin_bit_cast(
            bf16x8, *(const ushortx8*)&h_lds[ln * 280 + kc * 32 + q * 8]);
#pragma unroll
        for (int lt = 0; lt < 8; ++lt)
          acc[lt] = __builtin_amdgcn_mfma_f32_16x16x32_bf16(wf[lt][kc], hf,
                                                            acc[lt], 0, 0, 0);
      }
      if (ln < 8) {  // raw h-part preacts -> xch (bf16)
#pragma unroll
        for (int lt = 0; lt < 8; ++lt) {
          uint2 pk;
          pk.x = pack2bf(acc[lt][0], acc[lt][1]);
          pk.y = pack2bf(acc[lt][2], acc[lt][3]);
          *(uint2*)&xch[(w * 8 + ln) * 264 + lt * 16 + q * 4] = pk;
        }
      }
#pragma unroll
      for (int lt = 0; lt < 8; ++lt) acc[lt] = (floatx4){0.f, 0.f, 0.f, 0.f};
#pragma unroll
      for (int kc = 0; kc < 8; ++kc) {
        bf16x8 hf = __builtin_bit_cast(
            bf16x8, *(const ushortx8*)&h_lds[ln * 280 + kc * 32 + q * 8]);
#pragma unroll
        for (int lt = 0; lt < 5; ++lt)
          acc[lt] = __builtin_amdgcn_mfma_f32_16x16x32_bf16(wf[8 + lt][kc], hf,
                                                            acc[lt], 0, 0, 0);
#pragma unroll
        for (int lt = 5; lt < 8; ++lt) {
          bf16x8 wl = __builtin_bit_cast(
              bf16x8,
              *(const ushortx8*)&lds_w[(((w * 3 + (lt - 5)) * 8 + kc) * 64 +
                                        lane) * 8]);
          acc[lt] = __builtin_amdgcn_mfma_f32_16x16x32_bf16(wl, hf, acc[lt], 0,
                                                            0, 0);
        }
      }
      if (ln < 8) {
#pragma unroll
        for (int lt = 0; lt < 8; ++lt) {
          uint2 pk;
          pk.x = pack2bf(acc[lt][0], acc[lt][1]);
          pk.y = pack2bf(acc[lt][2], acc[lt][3]);
          *(uint2*)&xch[(w * 8 + ln) * 264 + (8 + lt) * 16 + q * 4] = pk;
        }
      }
      __syncthreads();  // S1: xch ready

      // ---- update: thread = (batch um, hidden hb..hb+7) ----
      float pre[4][8];
#pragma unroll
      for (int g4 = 0; g4 < 4; ++g4) {
        ushortx8 pv = *(const ushortx8*)&xch[(g4 * 8 + um) * 264 + hb];
        u64 xa = xgp[2 * g4], xb = xgp[2 * g4 + 1];
#pragma unroll
        for (int j = 0; j < 4; ++j) {
          pre[g4][j] = bf2f((uint32)pv[j]) + bf2f((uint32)(xa >> (16 * j)) & 0xffffu);
          pre[g4][4 + j] =
              bf2f((uint32)pv[4 + j]) + bf2f((uint32)(xb >> (16 * j)) & 0xffffu);
        }
      }
      ushortx8 hu;
#pragma unroll
      for (int j = 0; j < 8; ++j) {
        float iv = fast_sig(pre[0][j]);
        float fv = fast_sig(pre[1][j]);
        float gv = fast_tanh(pre[2][j]);
        float ov = fast_sig(pre[3][j]);
        c[j] = fv * c[j] + iv * gv;
        float hv = ov * fast_tanh(c[j]);
        hu[j] = f2bf(hv);
        if (t == T_ - 1) partial += hv * fc_w[hb + j];
      }
      *(ushortx8*)&h_lds[um * 280 + hb] = hu;
      if (tid == 0)
        __hip_atomic_store(prog + g * 16, t, __ATOMIC_RELAXED,
                           __HIP_MEMORY_SCOPE_AGENT);
      if (t < T_ - 1) {
        const int s = (t + 1) & Dmask;
        const int* fp = flags + (g * D + s) * 16;
        while (flagv < t + 2) flagv = aload(fp);
        __atomic_signal_fence(__ATOMIC_SEQ_CST);
        const unsigned short* rs = ringg + (size_t)s * 8192 + um * 1024 + hb;
#pragma unroll
        for (int g4 = 0; g4 < 4; ++g4) {
          xgp[2 * g4] = aload64((const u64*)(rs + g4 * 256));
          xgp[2 * g4 + 1] = aload64((const u64*)(rs + g4 * 256) + 1);
        }
        if (t + 2 < T_)  // speculative issue for next iteration's check
          flagv = aload(flags + (g * D + ((t + 2) & Dmask)) * 16);
      }
      __syncthreads();  // S2: h_lds(t) ready; xch consumed
    }
    // ---- FC: reduce 32 threads (same um) and write out ----
#pragma unroll
    for (int m2 = 1; m2 < 32; m2 <<= 1) partial += __shfl_xor(partial, m2);
    if ((tid & 31) == 0) out[g * MBATCH + um] = partial + fc_b[0];
  } else {
    // ================= PRODUCER: x_gates into the ring ====================
    const int g = bid - NG;
    bf16x8 wi[16][2];
    floatx4 biasv[16];
#pragma unroll
    for (int gt = 0; gt < 16; ++gt) {
      const int row = w * 256 + gt * 16 + ln;
#pragma unroll
      for (int kc = 0; kc < 2; ++kc) {
        const float* src = W_ih + (size_t)row * I_ + kc * 32 + q * 8;
        wi[gt][kc] = packbf8(*(const floatx4*)src, *(const floatx4*)(src + 4));
      }
      const int bn = w * 256 + gt * 16 + q * 4;
      floatx4 bi = *(const floatx4*)(b_ih + bn);
      floatx4 bh = *(const floatx4*)(b_hh + bn);
      biasv[gt] = bi + bh;
    }
    const float* xrow = x + (size_t)(g * MBATCH + (ln & 7)) * T_ * I_;
    floatx4 xf[4];
#pragma unroll
    for (int kc = 0; kc < 2; ++kc) {
      const float* s0 = xrow + kc * 32 + q * 8;
      xf[2 * kc] = *(const floatx4*)s0;
      xf[2 * kc + 1] = *(const floatx4*)(s0 + 4);
    }
    int* progp = prog + g * 16;
#pragma unroll 1
    for (int tp = 0; tp < T_; ++tp) {
      floatx4 xn[4];
      const bool more = (tp + 1 < T_);
      if (more) {
#pragma unroll
        for (int kc = 0; kc < 2; ++kc) {
          const float* s0 = xrow + (tp + 1) * I_ + kc * 32 + q * 8;
          xn[2 * kc] = *(const floatx4*)s0;
          xn[2 * kc + 1] = *(const floatx4*)(s0 + 4);
        }
      }
      if (tp >= D) {  // flow control: don't overwrite unconsumed slot
        while (aload(progp) < tp - D + 1) {
        }
      }
      bf16x8 bx0 = packbf8(xf[0], xf[1]);
      bf16x8 bx1 = packbf8(xf[2], xf[3]);
      floatx4 pa[16];
#pragma unroll
      for (int gt = 0; gt < 16; ++gt) pa[gt] = biasv[gt];
#pragma unroll
      for (int gt = 0; gt < 16; ++gt)
        pa[gt] =
            __builtin_amdgcn_mfma_f32_16x16x32_bf16(wi[gt][0], bx0, pa[gt], 0, 0, 0);
#pragma unroll
      for (int gt = 0; gt < 16; ++gt)
        pa[gt] =
            __builtin_amdgcn_mfma_f32_16x16x32_bf16(wi[gt][1], bx1, pa[gt], 0, 0, 0);
      const int s = tp & Dmask;
      if (ln < 8) {  // D[gate_row][batch]: rows gt*16+q*4..+3, batch=ln
        unsigned short* rs = ring + ((size_t)(g * D + s) * 8 + ln) * 1024;
#pragma unroll
        for (int gt = 0; gt < 16; ++gt) {
          u64 v = (u64)pack2bf(pa[gt][0], pa[gt][1]) |
                  ((u64)pack2bf(pa[gt][2], pa[gt][3]) << 32);
          __hip_atomic_store((u64*)(rs + w * 256 + gt * 16 + q * 4), v,
                             __ATOMIC_RELAXED, __HIP_MEMORY_SCOPE_AGENT);
        }
      }
      __syncthreads();  // drains vmcnt(0): slot data acked before flag
      if (tid == 0)
        __hip_atomic_store(flags + (g * D + s) * 16, tp + 1, __ATOMIC_RELAXED,
                           __HIP_MEMORY_SCOPE_AGENT);
      if (more) {
        xf[0] = xn[0]; xf[1] = xn[1]; xf[2] = xn[2]; xf[3] = xn[3];
      }
    }
  }
}

extern "C" void kernel_launch(void* const* d_in, const int* in_sizes, int n_in,
                              void* d_out, int out_size, void* d_ws,
                              size_t ws_size, hipStream_t stream) {
  const float* x    = (const float*)d_in[0];
  const float* W_ih = (const float*)d_in[1];
  const float* W_hh = (const float*)d_in[2];
  const float* b_ih = (const float*)d_in[3];
  const float* b_hh = (const float*)d_in[4];
  const float* fc_w = (const float*)d_in[5];
  const float* fc_b = (const float*)d_in[6];
  float* out = (float*)d_out;

  // ws layout: [0,4K) prog (32x16 ints), [4K,36K) flags (32*D*16 ints),
  // [64K, 64K + 32*D*16KB) ring. Poison 0xAAAAAAAA is negative => no init.
  int D = 1;
  for (int d = 16; d >= 1; d >>= 1) {
    size_t need = 65536 + (size_t)NG * d * 16384;
    if (ws_size >= need) { D = d; break; }
  }
  int* prog = (int*)d_ws;
  int* flags = (int*)((char*)d_ws + 4096);
  unsigned short* ring = (unsigned short*)((char*)d_ws + 65536);

  lstm_all<<<dim3(2 * NG), dim3(256), 0, stream>>>(
      x, W_ih, W_hh, b_ih, b_hh, fc_w, fc_b, out, prog, flags, ring, D, D - 1);
}

// Round 7
// 2840.775 us; speedup vs baseline: 2.0331x; 2.0331x over previous
//
#include <hip/hip_runtime.h>
#include <stdint.h>

// LSTM B=256,T=1024,I=64,H=256,O=1. fp32 in/out, bf16 MFMA internally.
//
// Round-7: round-3's MALL-scope exchange (sc0 sc1 everywhere — proven correct
// rounds 1-4; the round-5/6 sc0-only XCD experiment dead-latched) with the
// poll CONTENTION removed. Round-3 analysis: 256 blocks x 256 threads of
// uncached 32B data-polls every ~600cy ~= 8 TB/s of MALL read spam inflating
// all exchange latencies. Now: consumers first poll ONE 64B flag line per
// group (8 lanes, s_sleep backoff ~= 8KB/sweep grid-wide), then bulk-load the
// TAGGED 8B units once and verify tags in registers (retry loop is nearly
// dead code). Tags make flag/data reordering safe, so producers store flag
// immediately after units (no vmcnt drain on the critical path).
//
// 128 blocks = 16 batch-groups (16 batches) x 8 gate-slices (4 gates x 32
// hidden). Operand-swapped MFMA (A=W, B=h) -> C[gate_row][batch] (verified
// in round 4); all 4 gates of a hidden unit land in one wave -> in-wave LDS
// transpose, no extra barrier. 3 __syncthreads per step. Units: 8B
// {payload = 2x bf16 h, tag = step}; parity-reuse induction: tag-t units are
// only overwritten at end of step t+1, which requires all slices' verify(t)
// complete. Poison 0xAAAAAAAA: negative as int (flags) and never equals a
// live tag 1..1024 (units) => no ws init kernel. Dead-latch caps on both
// spin loops => wrong-answer-not-hang on any visibility failure.

#define T_ 1024
#define I_ 64
#define H_ 256
#define NGROUP 16
#define NSLICE 8
#define NBLK (NGROUP * NSLICE) /* 128 */
#define UPG 2048               /* 8B units per group per parity */
#define UPALL (NGROUP * UPG)   /* units per parity */
#define FLAG_CAP (1 << 18)
#define VERIFY_CAP (1 << 15)

typedef float floatx4 __attribute__((ext_vector_type(4)));
typedef __bf16 bf16x8 __attribute__((ext_vector_type(8)));
typedef unsigned short ushortx8 __attribute__((ext_vector_type(8)));
typedef unsigned int uintx4 __attribute__((ext_vector_type(4)));
typedef unsigned int uint32;
typedef unsigned long long u64;
typedef unsigned short ushort;

__device__ __forceinline__ ushort f2bf(float f) {
  uint32 u = __builtin_bit_cast(uint32, f);
  u = (u + 0x7FFFu + ((u >> 16) & 1u)) >> 16;  // RNE
  return (ushort)u;
}
__device__ __forceinline__ uint32 pack2bf(float a, float b) {
  return (uint32)f2bf(a) | ((uint32)f2bf(b) << 16);
}
__device__ __forceinline__ bf16x8 packbf8(floatx4 a, floatx4 b) {
  bf16x8 r;
  r[0] = (__bf16)a[0]; r[1] = (__bf16)a[1];
  r[2] = (__bf16)a[2]; r[3] = (__bf16)a[3];
  r[4] = (__bf16)b[0]; r[5] = (__bf16)b[1];
  r[6] = (__bf16)b[2]; r[7] = (__bf16)b[3];
  return r;
}
__device__ __forceinline__ float fast_sig(float v) {
  return 1.0f / (1.0f + __expf(-v));
}
__device__ __forceinline__ float fast_tanh(float v) {
  float e = __expf(2.0f * v);
  return 1.0f - 2.0f / (e + 1.0f);
}
__device__ __forceinline__ int aload(const int* p) {
  return __hip_atomic_load(p, __ATOMIC_RELAXED, __HIP_MEMORY_SCOPE_AGENT);
}
__device__ __forceinline__ void astore64(u64* p, u64 v) {
  __hip_atomic_store(p, v, __ATOMIC_RELAXED, __HIP_MEMORY_SCOPE_AGENT);
}

// Load 8 tagged units (64B) MALL-coherently. Early-clobber outputs: must not
// alias the address pair %4 (round-5 bug: aliasing clobbered the address).
__device__ __forceinline__ bool load8_check(const u64* up, int t, uintx4& a0,
                                            uintx4& a1, uintx4& a2,
                                            uintx4& a3) {
  asm volatile(
      "global_load_dwordx4 %0, %4, off sc0 sc1\n\t"
      "global_load_dwordx4 %1, %4, off offset:16 sc0 sc1\n\t"
      "global_load_dwordx4 %2, %4, off offset:32 sc0 sc1\n\t"
      "global_load_dwordx4 %3, %4, off offset:48 sc0 sc1\n\t"
      "s_waitcnt vmcnt(0)"
      : "=&v"(a0), "=&v"(a1), "=&v"(a2), "=&v"(a3)
      : "v"(up)
      : "memory");
  return ((int)a0[1] == t) & ((int)a0[3] == t) & ((int)a1[1] == t) &
         ((int)a1[3] == t) & ((int)a2[1] == t) & ((int)a2[3] == t) &
         ((int)a3[1] == t) & ((int)a3[3] == t);
}

__global__ __launch_bounds__(256, 1) void lstm_main(
    const float* __restrict__ x, const float* __restrict__ W_ih,
    const float* __restrict__ W_hh, const float* __restrict__ b_ih,
    const float* __restrict__ b_hh, const float* __restrict__ fc_w,
    int* __restrict__ flags, float* __restrict__ partials,
    u64* __restrict__ units) {
  const int tid = threadIdx.x;
  const int bid = blockIdx.x;
  const int g = bid >> 3;   // batch-group 0..15
  const int sl = bid & 7;   // gate-slice 0..7 (bid%8 spreads slices over XCDs)
  const int w = tid >> 6;   // wave 0..3
  const int lane = tid & 63;
  const int ln = lane & 15;
  const int q = lane >> 4;

  __shared__ __align__(16) ushort h_lds[16][264];  // [batch][hidden+pad]
  __shared__ float tsc[4][16 * 36];                // per-wave gate transpose
  __shared__ float fcred[4][16];

  // ---- weights as A-operand frags (m = gate*4+hid, k-chunk = q) ----
  // wave w owns hidden units sl*32 + w*8 + tau*4 + hid
  bf16x8 whh[2][8], wih[2][2];
  floatx4 biasv[2];
  {
    const int gate = ln >> 2, hid = ln & 3;
#pragma unroll
    for (int tau = 0; tau < 2; ++tau) {
      const int row = gate * 256 + sl * 32 + w * 8 + tau * 4 + hid;
#pragma unroll
      for (int kc = 0; kc < 8; ++kc) {
        const float* p = W_hh + (size_t)row * H_ + kc * 32 + q * 8;
        whh[tau][kc] = packbf8(*(const floatx4*)p, *(const floatx4*)(p + 4));
      }
#pragma unroll
      for (int kc = 0; kc < 2; ++kc) {
        const float* p = W_ih + (size_t)row * I_ + kc * 32 + q * 8;
        wih[tau][kc] = packbf8(*(const floatx4*)p, *(const floatx4*)(p + 4));
      }
      // acc reg j -> C row q*4+j -> gate=q, hidden sl*32+w*8+tau*4+j
#pragma unroll
      for (int j = 0; j < 4; ++j) {
        const int br = q * 256 + sl * 32 + w * 8 + tau * 4 + j;
        biasv[tau][j] = b_ih[br] + b_hh[br];
      }
    }
  }
  const int u0 = sl * 32 + w * 8 + 2 * q;  // this lane's 2 hidden units
  const float fcw0 = fc_w[u0], fcw1 = fc_w[u0 + 1];
  const float* xb = x + (size_t)(g * 16 + ln) * T_ * I_;  // batch = g*16+ln
  // store: unit (hpair = sl*16+w*4+q, batch = ln) -> contiguous 128B/chunk
  u64* const ust = units + (size_t)g * UPG + ((sl * 16 + w * 4 + q) * 16 + ln);
  const u64* const ubulk = units + (size_t)g * UPG + tid * 8;
  int* const myflag = flags + g * 16 + sl * 2;

  float c0 = 0.0f, c1 = 0.0f, partial = 0.0f;
  floatx4 xp0, xp1, xp2, xp3;
  {
    const float* xs = xb + q * 8;
    xp0 = *(const floatx4*)xs;
    xp1 = *(const floatx4*)(xs + 4);
    xp2 = *(const floatx4*)(xs + 32);
    xp3 = *(const floatx4*)(xs + 36);
  }

#pragma unroll 1
  for (int t = 0; t < T_; ++t) {
    // x-part MFMAs (independent of h)
    bf16x8 bx0 = packbf8(xp0, xp1);
    bf16x8 bx1 = packbf8(xp2, xp3);
    floatx4 acc0 = biasv[0], acc1 = biasv[1];
    acc0 = __builtin_amdgcn_mfma_f32_16x16x32_bf16(wih[0][0], bx0, acc0, 0, 0, 0);
    acc0 = __builtin_amdgcn_mfma_f32_16x16x32_bf16(wih[0][1], bx1, acc0, 0, 0, 0);
    acc1 = __builtin_amdgcn_mfma_f32_16x16x32_bf16(wih[1][0], bx0, acc1, 0, 0, 0);
    acc1 = __builtin_amdgcn_mfma_f32_16x16x32_bf16(wih[1][1], bx1, acc1, 0, 0, 0);

    if (t > 0) {
      // (1) cheap gate: 8 lanes poll the group's 64B flag line w/ backoff
      if (tid < 8) {
        const int* fp = flags + g * 16 + tid * 2;
        int it = 0;
        while (aload(fp) < t && ++it < FLAG_CAP) __builtin_amdgcn_s_sleep(1);
      }
      __syncthreads();  // S0
      // (2) bulk-load 8 tagged units, verify tags (usually 1 sweep)
      const u64* up = ubulk + (size_t)(t & 1) * UPALL;
      uintx4 a0, a1, a2, a3;
      int sweeps = 0;
      bool ok;
      do {
        ok = load8_check(up, t, a0, a1, a2, a3);
      } while (!__all(ok) && ++sweeps < VERIFY_CAP);
      // units tid*8+i: hpair p = tid>>1 (const), batch = (tid&1)*8 + i
      {
        const int b0 = (tid & 1) * 8, p = tid >> 1;
        ((uint32*)&h_lds[b0 + 0][0])[p] = a0[0];
        ((uint32*)&h_lds[b0 + 1][0])[p] = a0[2];
        ((uint32*)&h_lds[b0 + 2][0])[p] = a1[0];
        ((uint32*)&h_lds[b0 + 3][0])[p] = a1[2];
        ((uint32*)&h_lds[b0 + 4][0])[p] = a2[0];
        ((uint32*)&h_lds[b0 + 5][0])[p] = a2[2];
        ((uint32*)&h_lds[b0 + 6][0])[p] = a3[0];
        ((uint32*)&h_lds[b0 + 7][0])[p] = a3[2];
      }
      __syncthreads();  // S1: h_lds ready
      // h-part MFMAs: B frag = h[batch=ln][k]
      const ushort* hr = &h_lds[ln][0];
#pragma unroll
      for (int kc = 0; kc < 8; ++kc) {
        bf16x8 hf = __builtin_bit_cast(
            bf16x8, *(const ushortx8*)(hr + kc * 32 + q * 8));
        acc0 = __builtin_amdgcn_mfma_f32_16x16x32_bf16(whh[0][kc], hf, acc0, 0, 0, 0);
        acc1 = __builtin_amdgcn_mfma_f32_16x16x32_bf16(whh[1][kc], hf, acc1, 0, 0, 0);
      }
    }

    // ---- in-wave 4x8 gate transpose through per-wave LDS scratch ----
    // write pos = tau*16 + j*4 + gate(q); read float4 at 8q = gates of hid 2q
    {
      float* tb = &tsc[w][ln * 36];
      tb[0 + q] = acc0[0];  tb[4 + q] = acc0[1];
      tb[8 + q] = acc0[2];  tb[12 + q] = acc0[3];
      tb[16 + q] = acc1[0]; tb[20 + q] = acc1[1];
      tb[24 + q] = acc1[2]; tb[28 + q] = acc1[3];
    }
    floatx4 pe = *(const floatx4*)&tsc[w][ln * 36 + 8 * q];
    floatx4 po = *(const floatx4*)&tsc[w][ln * 36 + 8 * q + 4];
    // ---- update: lane owns (hidden u0, u0+1) x batch ln ----
    {
      float iv = fast_sig(pe[0]), fv = fast_sig(pe[1]);
      float gv = fast_tanh(pe[2]), ov = fast_sig(pe[3]);
      c0 = fv * c0 + iv * gv;
      float h0 = ov * fast_tanh(c0);
      iv = fast_sig(po[0]); fv = fast_sig(po[1]);
      gv = fast_tanh(po[2]); ov = fast_sig(po[3]);
      c1 = fv * c1 + iv * gv;
      float h1 = ov * fast_tanh(c1);
      u64 val = (u64)pack2bf(h0, h1) | ((u64)(uint32)(t + 1) << 32);
      astore64(ust + (size_t)((t + 1) & 1) * UPALL, val);
      if (t == T_ - 1) partial = h0 * fcw0 + h1 * fcw1;
    }
    // flag immediately (no drain): tag-verify makes early flag safe
    if (tid == 0)
      __hip_atomic_store(myflag, t + 1, __ATOMIC_RELAXED,
                         __HIP_MEMORY_SCOPE_AGENT);
    __syncthreads();  // S2: h_lds reads done before t+1 writes; stores drained
    if (t + 1 < T_) {
      const float* xs = xb + (t + 1) * I_ + q * 8;
      xp0 = *(const floatx4*)xs;
      xp1 = *(const floatx4*)(xs + 4);
      xp2 = *(const floatx4*)(xs + 32);
      xp3 = *(const floatx4*)(xs + 36);
    }
  }

  // ---- FC partial: reduce over q (shfl) then waves (LDS) ----
  partial += __shfl_xor(partial, 16);
  partial += __shfl_xor(partial, 32);
  if (lane < 16) fcred[w][lane] = partial;
  __syncthreads();
  if (tid < 16) {
    float v = fcred[0][tid] + fcred[1][tid] + fcred[2][tid] + fcred[3][tid];
    __hip_atomic_store(&partials[(g * 8 + sl) * 16 + tid], v, __ATOMIC_RELAXED,
                       __HIP_MEMORY_SCOPE_AGENT);
  }
}

__global__ void lstm_fc(const float* __restrict__ partials,
                        const float* __restrict__ fc_b,
                        float* __restrict__ out) {
  const int tid = threadIdx.x;  // batch = g*16 + ln = tid
  const int g = tid >> 4, ln = tid & 15;
  float s = fc_b[0];
#pragma unroll
  for (int sl = 0; sl < 8; ++sl)
    s += __hip_atomic_load(&partials[(g * 8 + sl) * 16 + ln], __ATOMIC_RELAXED,
                           __HIP_MEMORY_SCOPE_AGENT);
  out[tid] = s;
}

extern "C" void kernel_launch(void* const* d_in, const int* in_sizes, int n_in,
                              void* d_out, int out_size, void* d_ws,
                              size_t ws_size, hipStream_t stream) {
  const float* x    = (const float*)d_in[0];
  const float* W_ih = (const float*)d_in[1];
  const float* W_hh = (const float*)d_in[2];
  const float* b_ih = (const float*)d_in[3];
  const float* b_hh = (const float*)d_in[4];
  const float* fc_w = (const float*)d_in[5];
  const float* fc_b = (const float*)d_in[6];
  float* out = (float*)d_out;

  // ws: [0,1K) flags (16 groups x 8 slices x 8B, one 64B line per group);
  //     [1K,9K) partials (2048 f32); [16K, 16K+512K) units
  //     (2 parities x 16 groups x 2048 x 8B). Poison needs no init.
  int* flags = (int*)d_ws;
  float* partials = (float*)((char*)d_ws + 1024);
  u64* units = (u64*)((char*)d_ws + 16384);

  lstm_main<<<dim3(NBLK), dim3(256), 0, stream>>>(
      x, W_ih, W_hh, b_ih, b_hh, fc_w, flags, partials, units);
  lstm_fc<<<dim3(1), dim3(256), 0, stream>>>(partials, fc_b, out);
}